// Round 3
// baseline (2775.158 us; speedup 1.0000x reference)
//
#include <hip/hip_runtime.h>
#include <hip/hip_bf16.h>
#include <hip/hip_fp16.h>

// Problem constants
#define BB 64
#define SS 512
#define HH 512
#define EE 512

typedef _Float16 f16x4 __attribute__((ext_vector_type(4)));
typedef _Float16 f16x8 __attribute__((ext_vector_type(8)));
typedef float f32x4 __attribute__((ext_vector_type(4)));

#define NKREG 13  // k-tiles (of 32) held in registers (AGPR/VGPR unified)
#define NKLDS 3   // k-tiles read from LDS each step (k in [416,512))

static __device__ inline float tanhf_fast(float x) {
  float e = __expf(2.0f * x);
  return 1.0f - 2.0f / (e + 1.0f);
}

// out[m][n] = sum_k A[m][k] * W[n][k] + bias0[n] + bias1[n]
// GATHER: A row m comes from emb[tokens[m]] (f32). AF16: A is _Float16.
template <bool GATHER, bool AF16>
__global__ __launch_bounds__(256) void gemm_bias(
    const void* __restrict__ Aden, const int* __restrict__ tokens,
    const float* __restrict__ emb, const float* __restrict__ W,
    const float* __restrict__ bias0, const float* __restrict__ bias1,
    float* __restrict__ out, int M, int N, int K) {
  __shared__ float As[16][65];
  __shared__ float Bs[16][65];
  const int tx = threadIdx.x;  // 0..15
  const int ty = threadIdx.y;  // 0..15
  const int bm = blockIdx.y * 64;
  const int bn = blockIdx.x * 64;
  float acc[4][4] = {};

  for (int k0 = 0; k0 < K; k0 += 16) {
#pragma unroll
    for (int p = 0; p < 4; ++p) {
      const int m = bm + p * 16 + ty;
      float av;
      if constexpr (GATHER) {
        av = emb[(long)tokens[m] * EE + k0 + tx];
      } else if constexpr (AF16) {
        av = (float)((const _Float16*)Aden)[(long)m * K + k0 + tx];
      } else {
        av = ((const float*)Aden)[(long)m * K + k0 + tx];
      }
      As[tx][p * 16 + ty] = av;
    }
#pragma unroll
    for (int p = 0; p < 4; ++p) {
      const int n = bn + p * 16 + ty;
      Bs[tx][p * 16 + ty] = W[(long)n * K + k0 + tx];
    }
    __syncthreads();
#pragma unroll
    for (int k = 0; k < 16; ++k) {
      float a[4], bb[4];
#pragma unroll
      for (int i = 0; i < 4; ++i) a[i] = As[k][ty * 4 + i];
#pragma unroll
      for (int j = 0; j < 4; ++j) bb[j] = Bs[k][tx * 4 + j];
#pragma unroll
      for (int i = 0; i < 4; ++i)
#pragma unroll
        for (int j = 0; j < 4; ++j) acc[i][j] += a[i] * bb[j];
    }
    __syncthreads();
  }
#pragma unroll
  for (int i = 0; i < 4; ++i) {
    const int m = bm + ty * 4 + i;
#pragma unroll
    for (int j = 0; j < 4; ++j) {
      const int n = bn + tx * 4 + j;
      out[(long)m * N + n] = acc[i][j] + bias0[n] + bias1[n];
    }
  }
}

// Recurrence via MFMA. One wg per batch element, 512 threads = 8 waves.
// Wave w owns output rows [64w, 64w+64) as 4 row-tiles of 16.
// A (W_hh) fragments: 13 k-tiles in unified regs (MFMA reads AGPR directly),
// 3 k-tiles in LDS. B = h_{t-1} replicated across all 16 cols (lanes sharing
// (l>>4) read the same 16B -> cheap partial-broadcast ds_read_b128). Every
// lane's D is then valid for rows (l>>4)*4+j; epilogue spread over lanes lr<4.
__global__ __launch_bounds__(512, 2) void rec_mfma(
    const float* __restrict__ Whh,  // [512][512] f32
    const float* __restrict__ xw,   // [B*S][512] f32 (input part + biases)
    _Float16* __restrict__ hout     // [B*S][512] f16
) {
  extern __shared__ char smem[];
  f16x8* Alds = (f16x8*)smem;  // [NKLDS*4][512] f16x8 = 98304 B
  _Float16* hs = (_Float16*)(smem + (size_t)NKLDS * 4 * 512 * 16);  // [2][512]

  const int b = blockIdx.x;
  const int tid = threadIdx.x;
  const int w = tid >> 6;
  const int l = tid & 63;
  const int lr = l & 15;  // A-row / D-col within tile
  const int cg = l >> 4;  // k-subgroup (8-wide) / D-row group
  const long base = (long)b * SS;

  // ---- setup: A fragments in registers ----
  f16x8 aw[NKREG][4];
#pragma unroll
  for (int kt = 0; kt < NKREG; ++kt) {
#pragma unroll
    for (int rt = 0; rt < 4; ++rt) {
      const int row = 64 * w + 16 * rt + lr;
      const float4* p = (const float4*)(Whh + (long)row * HH + 32 * kt + 8 * cg);
      float4 f0 = p[0], f1 = p[1];
      aw[kt][rt] = (f16x8){(_Float16)f0.x, (_Float16)f0.y, (_Float16)f0.z,
                           (_Float16)f0.w, (_Float16)f1.x, (_Float16)f1.y,
                           (_Float16)f1.z, (_Float16)f1.w};
    }
  }
  // ---- setup: A k-tiles [NKREG,16) into LDS; slot s=(ktL*4+cgi) holds
  // W[row][416 + 8s .. +8] as f16x8, contiguous in row (conflict-free reads).
  {
    const int row = tid;
    const float4* p = (const float4*)(Whh + (long)row * HH + 32 * NKREG);
#pragma unroll
    for (int s = 0; s < NKLDS * 4; ++s) {
      float4 f0 = p[2 * s], f1 = p[2 * s + 1];
      Alds[(long)s * 512 + row] =
          (f16x8){(_Float16)f0.x, (_Float16)f0.y, (_Float16)f0.z, (_Float16)f0.w,
                  (_Float16)f1.x, (_Float16)f1.y, (_Float16)f1.z, (_Float16)f1.w};
    }
  }
  hs[tid] = (_Float16)0.f;  // h_{-1} = 0 in buffer 0
  __syncthreads();

  for (int t = 0; t < SS; ++t) {
    const int cur = (t & 1) * 512;
    const int nxt = 512 - cur;

    // xw values for this lane's epilogue rows (lanes lr<4 use them)
    float xs[4];
#pragma unroll
    for (int rt = 0; rt < 4; ++rt) {
      const int row = 64 * w + 16 * rt + 4 * cg + (lr & 3);
      xs[rt] = xw[(base + t) * HH + row];
    }

    f32x4 acc[4] = {{0.f, 0.f, 0.f, 0.f},
                    {0.f, 0.f, 0.f, 0.f},
                    {0.f, 0.f, 0.f, 0.f},
                    {0.f, 0.f, 0.f, 0.f}};
    const f16x8* hb = (const f16x8*)(hs + cur);
#pragma unroll
    for (int kt = 0; kt < NKREG; ++kt) {
      f16x8 bfrag = hb[kt * 4 + cg];
#pragma unroll
      for (int rt = 0; rt < 4; ++rt)
        acc[rt] = __builtin_amdgcn_mfma_f32_16x16x32_f16(aw[kt][rt], bfrag,
                                                         acc[rt], 0, 0, 0);
    }
#pragma unroll
    for (int kt = NKREG; kt < 16; ++kt) {
      f16x8 bfrag = hb[kt * 4 + cg];
#pragma unroll
      for (int rt = 0; rt < 4; ++rt) {
        f16x8 af = Alds[(long)((kt - NKREG) * 4 + cg) * 512 + 64 * w + 16 * rt + lr];
        acc[rt] = __builtin_amdgcn_mfma_f32_16x16x32_f16(af, bfrag,
                                                         acc[rt], 0, 0, 0);
      }
    }

    // epilogue: lanes lr<4 own j=lr; D row = (cg)*4 + j within tile
    if (lr < 4) {
      const int j = lr;
#pragma unroll
      for (int rt = 0; rt < 4; ++rt) {
        const int row = 64 * w + 16 * rt + 4 * cg + j;
        float v = tanhf_fast(xs[rt] + acc[rt][j]);
        hs[nxt + row] = (_Float16)v;
      }
    }
    __syncthreads();
    hout[(base + t) * HH + tid] = hs[nxt + tid];
  }
}

// out[m][c] = sum_h h1[m][h] * Wfc[c][h] + bfc[c];  one wave per row m
__global__ __launch_bounds__(256) void fc_kernel(
    const _Float16* __restrict__ h1, const float* __restrict__ Wfc,
    const float* __restrict__ bfc, float* __restrict__ out) {
  const int lane = threadIdx.x & 63;
  const int wid = threadIdx.x >> 6;
  const long m = (long)blockIdx.x * 4 + wid;
  f16x8 hv = ((const f16x8*)(h1 + m * HH))[lane];
  const float4* w0 = (const float4*)(Wfc);
  const float4* w1 = (const float4*)(Wfc + HH);
  float4 a0 = w0[2 * lane], a1 = w0[2 * lane + 1];
  float4 b0 = w1[2 * lane], b1 = w1[2 * lane + 1];
  float p0 = (float)hv[0] * a0.x + (float)hv[1] * a0.y + (float)hv[2] * a0.z +
             (float)hv[3] * a0.w + (float)hv[4] * a1.x + (float)hv[5] * a1.y +
             (float)hv[6] * a1.z + (float)hv[7] * a1.w;
  float p1 = (float)hv[0] * b0.x + (float)hv[1] * b0.y + (float)hv[2] * b0.z +
             (float)hv[3] * b0.w + (float)hv[4] * b1.x + (float)hv[5] * b1.y +
             (float)hv[6] * b1.z + (float)hv[7] * b1.w;
#pragma unroll
  for (int off = 32; off; off >>= 1) {
    p0 += __shfl_down(p0, off);
    p1 += __shfl_down(p1, off);
  }
  if (lane == 0) {
    out[m * 2 + 0] = p0 + bfc[0];
    out[m * 2 + 1] = p1 + bfc[1];
  }
}

extern "C" void kernel_launch(void* const* d_in, const int* in_sizes, int n_in,
                              void* d_out, int out_size, void* d_ws, size_t ws_size,
                              hipStream_t stream) {
  const int* tokens = (const int*)d_in[0];
  const float* emb = (const float*)d_in[1];
  const float* W_ih0 = (const float*)d_in[2];
  const float* b_ih0 = (const float*)d_in[3];
  const float* W_hh0 = (const float*)d_in[4];
  const float* b_hh0 = (const float*)d_in[5];
  const float* W_ih1 = (const float*)d_in[6];
  const float* b_ih1 = (const float*)d_in[7];
  const float* W_hh1 = (const float*)d_in[8];
  const float* b_hh1 = (const float*)d_in[9];
  const float* W_fc = (const float*)d_in[10];
  const float* b_fc = (const float*)d_in[11];
  float* out = (float*)d_out;

  const long MS = (long)BB * SS;          // 32768
  float* bufA = (float*)d_ws;             // xw buffer [MS][512] f32 (64 MB)
  _Float16* bufB = (_Float16*)(bufA + MS * HH);  // h buffer [MS][512] f16 (32 MB)

  const int rec_lds = NKLDS * 4 * 512 * 16 + 2 * 512 * 2;  // 100352 B

  dim3 gb(16, 16);
  // xw0 = gather(emb, tokens) @ W_ih0^T + b_ih0 + b_hh0
  gemm_bias<true, false><<<dim3(8, 512), gb, 0, stream>>>(
      nullptr, tokens, emb, W_ih0, b_ih0, b_hh0, bufA, (int)MS, HH, EE);
  // layer 0 recurrence -> h0 (f16) in bufB
  rec_mfma<<<64, 512, rec_lds, stream>>>(W_hh0, bufA, bufB);
  // xw1 = h0 @ W_ih1^T + b_ih1 + b_hh1  (A is f16)
  gemm_bias<false, true><<<dim3(8, 512), gb, 0, stream>>>(
      bufB, nullptr, nullptr, W_ih1, b_ih1, b_hh1, bufA, (int)MS, HH, HH);
  // layer 1 recurrence -> h1 (f16) in bufB (overwrites h0, no longer needed)
  rec_mfma<<<64, 512, rec_lds, stream>>>(W_hh1, bufA, bufB);
  // FC
  fc_kernel<<<8192, 256, 0, stream>>>(bufB, W_fc, b_fc, out);
}

// Round 5
// 1832.282 us; speedup vs baseline: 1.5146x; 1.5146x over previous
//
#include <hip/hip_runtime.h>
#include <hip/hip_bf16.h>
#include <hip/hip_fp16.h>

// Problem constants
#define BB 64
#define SS 512
#define HH 512
#define EE 512

typedef _Float16 h2 __attribute__((ext_vector_type(2)));
typedef _Float16 f16x8 __attribute__((ext_vector_type(8)));
typedef float f32x4 __attribute__((ext_vector_type(4)));

#define PICK(v, I) (__builtin_shufflevector((v), (v), 2 * (I), 2 * (I) + 1))

static __device__ inline float dot2f(h2 a, h2 b, float c) {
#if __has_builtin(__builtin_amdgcn_fdot2)
  return __builtin_amdgcn_fdot2(a, b, c, false);
#else
  return c + (float)a[0] * (float)b[0] + (float)a[1] * (float)b[1];
#endif
}

static __device__ inline float tanhf_fast(float x) {
  float e = __expf(2.0f * x);
  return 1.0f - 2.0f / (e + 1.0f);
}

static __device__ inline f16x8 cvt8(float4 f0, float4 f1) {
  return (f16x8){(_Float16)f0.x, (_Float16)f0.y, (_Float16)f0.z, (_Float16)f0.w,
                 (_Float16)f1.x, (_Float16)f1.y, (_Float16)f1.z, (_Float16)f1.w};
}

// ---------------------------------------------------------------------------
// MFMA GEMM: out[m][n] = sum_k A[m][k]*W[n][k] + bias0[n] + bias1[n]
// W-panel [128 n][512 k] f16 resident in LDS (XOR-swizzled, staged once).
// A streamed from global: GATHER -> emb[tokens[m]] f32 (cvt f16), else f16.
// Grid: (M/512, 512/128) = (64, 4); 256 thr = 4 waves; wave owns 128 M-rows.
// MFMA 16x16x32_f16: A lane l: row=l&15, k=(l>>4)*8+j;
// B lane l: n=l&15, k=(l>>4)*8+j; D lane l: n=l&15, m-row=(l>>4)*4+reg [m89].
// ---------------------------------------------------------------------------
template <bool GATHER>
__global__ __launch_bounds__(256) void gemm_mfma(
    const _Float16* __restrict__ Af16, const int* __restrict__ tokens,
    const float* __restrict__ emb, const float* __restrict__ W,
    const float* __restrict__ bias0, const float* __restrict__ bias1,
    float* __restrict__ out) {
  __shared__ f16x8 wlds[128 * 64];  // [n_loc][slot], slot=(k/8)^(n_loc&7); 128KB
  const int tid = threadIdx.x;
  const int mg = blockIdx.x;       // 64 M-groups of 512 rows
  const int n0 = blockIdx.y * 128; // 4 N-groups

  // ---- stage W panel (f32 -> f16, swizzled) ----
  {
    const int n_loc = tid >> 1;  // 0..127
    const int kh = tid & 1;      // k half (256 each)
    const float4* wrow = (const float4*)(W + (long)(n0 + n_loc) * HH + kh * 256);
#pragma unroll
    for (int i = 0; i < 32; ++i) {
      f16x8 v = cvt8(wrow[2 * i], wrow[2 * i + 1]);
      const int slog = kh * 32 + i;
      wlds[n_loc * 64 + (slog ^ (n_loc & 7))] = v;
    }
  }
  __syncthreads();

  const int w = tid >> 6;
  const int l = tid & 63;
  const int lr = l & 15;
  const int cg = l >> 4;

  float bsum[8];
#pragma unroll
  for (int nt = 0; nt < 8; ++nt) {
    const int n = n0 + nt * 16 + lr;
    bsum[nt] = bias0[n] + bias1[n];
  }

  for (int mt = 0; mt < 8; ++mt) {
    const int m0 = mg * 512 + w * 128 + mt * 16;
    const int row = m0 + lr;
    const float* arow_f32 = nullptr;
    const _Float16* arow_f16 = nullptr;
    if constexpr (GATHER) {
      arow_f32 = emb + (long)tokens[row] * EE;
    } else {
      arow_f16 = Af16 + (long)row * HH;
    }

    f32x4 acc[8] = {{0.f, 0.f, 0.f, 0.f}, {0.f, 0.f, 0.f, 0.f},
                    {0.f, 0.f, 0.f, 0.f}, {0.f, 0.f, 0.f, 0.f},
                    {0.f, 0.f, 0.f, 0.f}, {0.f, 0.f, 0.f, 0.f},
                    {0.f, 0.f, 0.f, 0.f}, {0.f, 0.f, 0.f, 0.f}};
#pragma unroll
    for (int kt = 0; kt < 16; ++kt) {
      f16x8 af;
      if constexpr (GATHER) {
        const float4* p = (const float4*)(arow_f32 + kt * 32 + cg * 8);
        af = cvt8(p[0], p[1]);
      } else {
        af = *(const f16x8*)(arow_f16 + kt * 32 + cg * 8);
      }
#pragma unroll
      for (int nt = 0; nt < 8; ++nt) {
        f16x8 bf = wlds[(nt * 16 + lr) * 64 + ((kt * 4 + cg) ^ (lr & 7))];
        acc[nt] = __builtin_amdgcn_mfma_f32_16x16x32_f16(af, bf, acc[nt], 0, 0, 0);
      }
    }
#pragma unroll
    for (int nt = 0; nt < 8; ++nt) {
      const int n = n0 + nt * 16 + lr;
#pragma unroll
      for (int j = 0; j < 4; ++j) {
        const int m = m0 + cg * 4 + j;
        out[(long)m * HH + n] = acc[nt][j] + bsum[nt];
      }
    }
  }
}

// ---------------------------------------------------------------------------
// Recurrence: h_t = tanh(xw_t + W_hh h_{t-1}). One wg / batch elem, 512 thr =
// 1 thr per output row. W row r: cols [0,416) as 208 h2 in regs (VGPR+AGPR),
// cols [416,512) as 12 f16x8 chunks in LDS (96KB, contiguous-by-row reads).
// h_{t-1} double-buffered in LDS f16; hout store deferred into next step's
// compute shadow (no vmcnt-drain stall at the barrier); xw prefetched 1 step.
// ---------------------------------------------------------------------------
__global__ __launch_bounds__(512, 2) void rec_v3(
    const float* __restrict__ Whh,  // [512][512] f32
    const float* __restrict__ xw,   // [B*S][512] f32
    _Float16* __restrict__ hout     // [B*S][512] f16
) {
  extern __shared__ char smem[];
  f16x8* wlds = (f16x8*)smem;                       // [12][512] = 96KB
  _Float16* hs = (_Float16*)(smem + 12 * 512 * 16);  // [2][512] f16

  const int b = blockIdx.x;
  const int r = threadIdx.x;
  const long base = (long)b * SS;

  // ---- setup ----
  h2 w[208];
  {
    const float2* wrow2 = (const float2*)(Whh + (long)r * HH);
#pragma unroll
    for (int q = 0; q < 208; ++q) {
      float2 f = wrow2[q];
      h2 v;
      v[0] = (_Float16)f.x;
      v[1] = (_Float16)f.y;
      w[q] = v;
    }
    const float4* wrow4 = (const float4*)(Whh + (long)r * HH + 416);
#pragma unroll
    for (int s = 0; s < 12; ++s)
      wlds[s * 512 + r] = cvt8(wrow4[2 * s], wrow4[2 * s + 1]);
  }
  hs[r] = (_Float16)0.f;  // h_{-1} = 0 in buffer 0
  __syncthreads();

  float xwv = xw[base * HH + r];
  float hval_prev = 0.f;

  for (int t = 0; t < SS; ++t) {
    // deferred hout store for t-1 (drains during this step's compute)
    if (t > 0) hout[(base + t - 1) * HH + r] = (_Float16)hval_prev;
    // prefetch next step's xw
    float xw_next = (t + 1 < SS) ? xw[(base + t + 1) * HH + r] : 0.f;

    const f16x8* hb = (const f16x8*)(hs + (t & 1) * 512);
    float a0 = 0.f, a1 = 0.f, a2 = 0.f, a3 = 0.f;
#pragma unroll
    for (int j = 0; j < 52; ++j) {  // cols [0,416) : W in regs, h broadcast
      f16x8 hv = hb[j];
      a0 = dot2f(w[4 * j + 0], PICK(hv, 0), a0);
      a1 = dot2f(w[4 * j + 1], PICK(hv, 1), a1);
      a2 = dot2f(w[4 * j + 2], PICK(hv, 2), a2);
      a3 = dot2f(w[4 * j + 3], PICK(hv, 3), a3);
    }
#pragma unroll
    for (int s = 0; s < 12; ++s) {  // cols [416,512) : W from LDS
      f16x8 wv = wlds[s * 512 + r];
      f16x8 hv = hb[52 + s];
      a0 = dot2f(PICK(wv, 0), PICK(hv, 0), a0);
      a1 = dot2f(PICK(wv, 1), PICK(hv, 1), a1);
      a2 = dot2f(PICK(wv, 2), PICK(hv, 2), a2);
      a3 = dot2f(PICK(wv, 3), PICK(hv, 3), a3);
    }
    float p = (a0 + a1) + (a2 + a3);
    float hval = tanhf_fast(xwv + p);

    hs[(512 - (t & 1) * 512) + r] = (_Float16)hval;
    __syncthreads();
    xwv = xw_next;
    hval_prev = hval;
  }
  hout[(base + SS - 1) * HH + r] = (_Float16)hval_prev;
}

// out[m][c] = sum_h h1[m][h] * Wfc[c][h] + bfc[c];  one wave per row m
__global__ __launch_bounds__(256) void fc_kernel(
    const _Float16* __restrict__ h1, const float* __restrict__ Wfc,
    const float* __restrict__ bfc, float* __restrict__ out) {
  const int lane = threadIdx.x & 63;
  const int wid = threadIdx.x >> 6;
  const long m = (long)blockIdx.x * 4 + wid;
  f16x8 hv = ((const f16x8*)(h1 + m * HH))[lane];
  const float4* w0 = (const float4*)(Wfc);
  const float4* w1 = (const float4*)(Wfc + HH);
  float4 a0 = w0[2 * lane], a1 = w0[2 * lane + 1];
  float4 b0 = w1[2 * lane], b1 = w1[2 * lane + 1];
  float p0 = (float)hv[0] * a0.x + (float)hv[1] * a0.y + (float)hv[2] * a0.z +
             (float)hv[3] * a0.w + (float)hv[4] * a1.x + (float)hv[5] * a1.y +
             (float)hv[6] * a1.z + (float)hv[7] * a1.w;
  float p1 = (float)hv[0] * b0.x + (float)hv[1] * b0.y + (float)hv[2] * b0.z +
             (float)hv[3] * b0.w + (float)hv[4] * b1.x + (float)hv[5] * b1.y +
             (float)hv[6] * b1.z + (float)hv[7] * b1.w;
#pragma unroll
  for (int off = 32; off; off >>= 1) {
    p0 += __shfl_down(p0, off);
    p1 += __shfl_down(p1, off);
  }
  if (lane == 0) {
    out[m * 2 + 0] = p0 + bfc[0];
    out[m * 2 + 1] = p1 + bfc[1];
  }
}

extern "C" void kernel_launch(void* const* d_in, const int* in_sizes, int n_in,
                              void* d_out, int out_size, void* d_ws, size_t ws_size,
                              hipStream_t stream) {
  const int* tokens = (const int*)d_in[0];
  const float* emb = (const float*)d_in[1];
  const float* W_ih0 = (const float*)d_in[2];
  const float* b_ih0 = (const float*)d_in[3];
  const float* W_hh0 = (const float*)d_in[4];
  const float* b_hh0 = (const float*)d_in[5];
  const float* W_ih1 = (const float*)d_in[6];
  const float* b_ih1 = (const float*)d_in[7];
  const float* W_hh1 = (const float*)d_in[8];
  const float* b_hh1 = (const float*)d_in[9];
  const float* W_fc = (const float*)d_in[10];
  const float* b_fc = (const float*)d_in[11];
  float* out = (float*)d_out;

  const long MS = (long)BB * SS;                 // 32768
  float* bufA = (float*)d_ws;                    // xw [MS][512] f32 (64MB)
  _Float16* bufB = (_Float16*)(bufA + MS * HH);  // h  [MS][512] f16 (32MB)

  const int rec_lds = 12 * 512 * 16 + 2 * 512 * 2;  // 100352 B

  // xw0 = gather(emb, tokens) @ W_ih0^T + b_ih0 + b_hh0
  gemm_mfma<true><<<dim3(64, 4), 256, 0, stream>>>(
      nullptr, tokens, emb, W_ih0, b_ih0, b_hh0, bufA);
  // layer 0 recurrence -> h0 (f16) in bufB
  rec_v3<<<64, 512, rec_lds, stream>>>(W_hh0, bufA, bufB);
  // xw1 = h0 @ W_ih1^T + b_ih1 + b_hh1  (A = h0 f16)
  gemm_mfma<false><<<dim3(64, 4), 256, 0, stream>>>(
      bufB, nullptr, nullptr, W_ih1, b_ih1, b_hh1, bufA);
  // layer 1 recurrence -> h1 (f16) in bufB
  rec_v3<<<64, 512, rec_lds, stream>>>(W_hh1, bufA, bufB);
  // FC
  fc_kernel<<<8192, 256, 0, stream>>>(bufB, W_fc, b_fc, out);
}